// Round 15
// baseline (215.675 us; speedup 1.0000x reference)
//
#include <hip/hip_runtime.h>
#include <math.h>

typedef __attribute__((ext_vector_type(4))) float f32x4;
typedef __attribute__((ext_vector_type(8))) __bf16 bf16x8;

static constexpr int WG_OFF = 0;
static constexpr int WL_OFF = 163840;
static constexpr int WQ_OFF = 327680;
static constexpr int WK_OFF = 393216;
static constexpr int WV_OFF = 458752;
static constexpr int WO_OFF = 524288;
static constexpr int W1_OFF = 589824;
static constexpr int W_TOTAL = 622592;

__device__ __forceinline__ unsigned short f2bf(float f) {
  unsigned u = __builtin_bit_cast(unsigned, f);
  u += 0x7FFFu + ((u >> 16) & 1u);
  return (unsigned short)(u >> 16);
}

__device__ __forceinline__ f32x4 mfma16(bf16x8 a, bf16x8 b, f32x4 c) {
  return __builtin_amdgcn_mfma_f32_16x16x32_bf16(a, b, c, 0, 0, 0);
}
__device__ __forceinline__ f32x4 fzero4() {
  f32x4 v; v[0] = 0.f; v[1] = 0.f; v[2] = 0.f; v[3] = 0.f; return v;
}

// B fragment: frag-major layout in ws; one coalesced 1KB wave-read from global (L2).
__device__ __forceinline__ bf16x8 ldB(const unsigned short* __restrict__ ws, int fragIdx, int lane) {
  return *(const bf16x8*)(ws + (size_t)(fragIdx * 64 + lane) * 8);
}

// A-frag (16 rows x 32 k) from XOR-swizzled LDS tile with row byte-stride STRIDE.
template <int STRIDE>
__device__ __forceinline__ bf16x8 ldA(const char* s, int row, int kbyte) {
  return *(const bf16x8*)(s + row * STRIDE + (kbyte ^ ((row & 7) << 4)));
}

__device__ __forceinline__ void stC(char* s, int row, int col, float v) {
  *(__bf16*)(s + row * 512 + ((col * 2) ^ ((row & 7) << 4))) = (__bf16)v;
}
__device__ __forceinline__ float ldC(const char* s, int row, int col) {
  return (float)*(const __bf16*)(s + row * 512 + ((col * 2) ^ ((row & 7) << 4)));
}

__device__ __forceinline__ bf16x8 cvt8(float4 a, float4 b) {
  bf16x8 t;
  t[0] = (__bf16)a.x; t[1] = (__bf16)a.y; t[2] = (__bf16)a.z; t[3] = (__bf16)a.w;
  t[4] = (__bf16)b.x; t[5] = (__bf16)b.y; t[6] = (__bf16)b.z; t[7] = (__bf16)b.w;
  return t;
}

template <int N>
__device__ __forceinline__ void red16(float* v) {
#pragma unroll
  for (int m = 1; m < 16; m <<= 1) {
#pragma unroll
    for (int i = 0; i < N; ++i) v[i] += __shfl_xor(v[i], m);
  }
}

// stage [32 rows][640] fp32 -> bf16 swizzled LDS (row stride 1280B)
__device__ __forceinline__ void stageA32(const float* __restrict__ A, char* sA, int tid) {
#pragma unroll
  for (int i = 0; i < 5; ++i) {
    const int idx = i * 512 + tid;
    const int row = idx / 80;
    const int c8 = idx - row * 80;
    const float* ap = A + (size_t)idx * 8;
    float4 f0 = *(const float4*)ap;
    float4 f1 = *(const float4*)(ap + 4);
    *(bf16x8*)(sA + row * 1280 + ((c8 * 16) ^ ((row & 7) << 4))) = cvt8(f0, f1);
  }
}

// proj: [32 rows x 640] @ W -> wave's 2 col-frags; unroll capped at 2.
__device__ __forceinline__ void proj640(const char* sA, const unsigned short* __restrict__ wsW,
                                        const float* __restrict__ bias, char* sDst,
                                        int f0, int lane) {
  const int l15 = lane & 15, kg4 = lane >> 4;
  f32x4 acc[2][2];
#pragma unroll
  for (int m = 0; m < 2; ++m)
#pragma unroll
    for (int n = 0; n < 2; ++n) acc[m][n] = fzero4();
#pragma unroll 2
  for (int kt = 0; kt < 20; ++kt) {
    bf16x8 b0 = ldB(wsW, kt * 16 + f0, lane);
    bf16x8 b1 = ldB(wsW, kt * 16 + f0 + 1, lane);
    const int kb = kt * 64 + kg4 * 16;
#pragma unroll
    for (int m = 0; m < 2; ++m) {
      bf16x8 a = ldA<1280>(sA, m * 16 + l15, kb);
      acc[m][0] = mfma16(a, b0, acc[m][0]);
      acc[m][1] = mfma16(a, b1, acc[m][1]);
    }
  }
#pragma unroll
  for (int n = 0; n < 2; ++n) {
    const int col = (f0 + n) * 16 + l15;
    const float bv = bias[col];
#pragma unroll
    for (int m = 0; m < 2; ++m)
#pragma unroll
      for (int r = 0; r < 4; ++r)
        stC(sDst, m * 16 + kg4 * 4 + r, col, acc[m][n][r] + bv);
  }
}

// K=256 gemm, wave's 2 col-frags; unroll capped at 2 (bounds B-load hoisting).
__device__ __forceinline__ void gemm256(const char* sA, const unsigned short* __restrict__ wsW,
                                        int f0, f32x4 (&acc)[2][2], int lane) {
  const int l15 = lane & 15, kg4 = lane >> 4;
#pragma unroll 2
  for (int kt = 0; kt < 8; ++kt) {
    bf16x8 b0 = ldB(wsW, kt * 16 + f0, lane);
    bf16x8 b1 = ldB(wsW, kt * 16 + f0 + 1, lane);
    const int kb = kt * 64 + kg4 * 16;
#pragma unroll
    for (int m = 0; m < 2; ++m) {
      bf16x8 a = ldA<512>(sA, m * 16 + l15, kb);
      acc[m][0] = mfma16(a, b0, acc[m][0]);
      acc[m][1] = mfma16(a, b1, acc[m][1]);
    }
  }
}

__global__ void convert_w(const float* __restrict__ Wg, const float* __restrict__ Wl,
                          const float* __restrict__ Win, const float* __restrict__ Wout,
                          const float* __restrict__ W1, unsigned short* __restrict__ ws) {
  const int tid = blockIdx.x * 256 + threadIdx.x;
  if (tid >= W_TOTAL) return;
  const float* src;
  int stride, coloff, base, lognf;
  if (tid < WL_OFF)      { src = Wg;   stride = 256; coloff = 0;   base = WG_OFF; lognf = 4; }
  else if (tid < WQ_OFF) { src = Wl;   stride = 256; coloff = 0;   base = WL_OFF; lognf = 4; }
  else if (tid < WK_OFF) { src = Win;  stride = 768; coloff = 0;   base = WQ_OFF; lognf = 4; }
  else if (tid < WV_OFF) { src = Win;  stride = 768; coloff = 256; base = WK_OFF; lognf = 4; }
  else if (tid < WO_OFF) { src = Win;  stride = 768; coloff = 512; base = WV_OFF; lognf = 4; }
  else if (tid < W1_OFF) { src = Wout; stride = 256; coloff = 0;   base = WO_OFF; lognf = 4; }
  else                   { src = W1;   stride = 128; coloff = 0;   base = W1_OFF; lognf = 3; }
  const int idx = tid - base;
  const int j = idx & 7;
  const int lane = (idx >> 3) & 63;
  const int fl = idx >> 9;
  const int n = fl & ((1 << lognf) - 1);
  const int kt = fl >> lognf;
  const int k = kt * 32 + (lane >> 4) * 8 + j;
  const int col = coloff + n * 16 + (lane & 15);
  ws[tid] = f2bf(src[k * stride + col]);
}

__global__ __launch_bounds__(512)
__attribute__((amdgpu_waves_per_eu(4, 4)))  // 128 unified regs/wave; 2 blocks/CU (LDS-capped)
void dca_fused(
    const float* __restrict__ gdiff, const float* __restrict__ ldiff,
    const float* __restrict__ bg, const float* __restrict__ bl,
    const float* __restrict__ bin, const float* __restrict__ bout,
    const float* __restrict__ gamma, const float* __restrict__ beta,
    const float* __restrict__ b1, const float* __restrict__ W2,
    const float* __restrict__ b2, const unsigned short* __restrict__ wsw,
    float* __restrict__ out) {
  __shared__ __align__(16) char sMem[73728];
  char* sA = sMem;                      // [32][1280B] staged A (40960 B)
  char* sG = sMem + 40960;              // [32][512B] g tile -> x -> y
  char* sL = sMem + 57344;              // [32][512B] l tile -> ctx
  float* sSc = (float*)sMem;            // [8][32][2] score partials (aliases dead sA)
  float* sLN = (float*)(sMem + 2048);   // [8][32][2] LN partials
  float* sMu = (float*)(sMem + 4096);   // [32][2]
  float* sPO = (float*)(sMem + 4352);   // [8][32]

  const int tid = threadIdx.x;
  const int blk = blockIdx.x;
  const int lane = tid & 63, l15 = lane & 15, kg4 = lane >> 4;
  const int w = tid >> 6;
  const int f0 = w * 2;

  // ---- phase 1: stage g -> proj g ; stage l -> proj l (R13 form; R14 dbuf was neutral)
  stageA32(gdiff + (size_t)blk * 32 * 640, sA, tid);
  __syncthreads();
  proj640(sA, wsw + WG_OFF, bg, sG, f0, lane);
  __syncthreads();
  stageA32(ldiff + (size_t)blk * 32 * 640, sA, tid);
  __syncthreads();
  proj640(sA, wsw + WL_OFF, bl, sL, f0, lane);
  __syncthreads();

  // ---- phase 2: MEGA-MERGED q+kg+kl+vg+vl in ONE 8-kt pass (20 MFMA per kt;
  //      every A-load feeds 10 MFMAs). v-gemm latency leaves the critical path:
  //      after softmax, ctx is a pure register combine.
  f32x4 q[2][2], kg[2][2], kl[2][2], vg[2][2], vl[2][2];
#pragma unroll
  for (int m = 0; m < 2; ++m)
#pragma unroll
    for (int n = 0; n < 2; ++n) {
      q[m][n] = fzero4(); kg[m][n] = fzero4(); kl[m][n] = fzero4();
      vg[m][n] = fzero4(); vl[m][n] = fzero4();
    }
#pragma unroll 1
  for (int kt = 0; kt < 8; ++kt) {
    bf16x8 bq0 = ldB(wsw + WQ_OFF, kt * 16 + f0, lane);
    bf16x8 bq1 = ldB(wsw + WQ_OFF, kt * 16 + f0 + 1, lane);
    bf16x8 bk0 = ldB(wsw + WK_OFF, kt * 16 + f0, lane);
    bf16x8 bk1 = ldB(wsw + WK_OFF, kt * 16 + f0 + 1, lane);
    bf16x8 bv0 = ldB(wsw + WV_OFF, kt * 16 + f0, lane);
    bf16x8 bv1 = ldB(wsw + WV_OFF, kt * 16 + f0 + 1, lane);
    const int kb = kt * 64 + kg4 * 16;
#pragma unroll
    for (int m = 0; m < 2; ++m) {
      bf16x8 g = ldA<512>(sG, m * 16 + l15, kb);
      bf16x8 l = ldA<512>(sL, m * 16 + l15, kb);
      q[m][0] = mfma16(g, bq0, q[m][0]);
      q[m][1] = mfma16(g, bq1, q[m][1]);
      kg[m][0] = mfma16(g, bk0, kg[m][0]);
      kg[m][1] = mfma16(g, bk1, kg[m][1]);
      kl[m][0] = mfma16(l, bk0, kl[m][0]);
      kl[m][1] = mfma16(l, bk1, kl[m][1]);
      vg[m][0] = mfma16(g, bv0, vg[m][0]);
      vg[m][1] = mfma16(g, bv1, vg[m][1]);
      vl[m][0] = mfma16(l, bv0, vl[m][0]);
      vl[m][1] = mfma16(l, bv1, vl[m][1]);
    }
  }
  // scores: q gets its bias (k bias cancels in s0-s1); q/kg/kl die here
  float s[16];
#pragma unroll
  for (int m = 0; m < 2; ++m) {
#pragma unroll
    for (int r = 0; r < 4; ++r) {
      float t0 = 0.f, t1 = 0.f;
#pragma unroll
      for (int n = 0; n < 2; ++n) {
        const float qv = q[m][n][r] + bin[(f0 + n) * 16 + l15];
        t0 += qv * kg[m][n][r];
        t1 += qv * kl[m][n][r];
      }
      s[m * 4 + r] = t0;
      s[8 + m * 4 + r] = t1;
    }
  }
  red16<16>(s);
  if (l15 < 2) {
#pragma unroll
    for (int r = 0; r < 4; ++r) {
      const int row = l15 * 16 + kg4 * 4 + r;
      sSc[(w * 32 + row) * 2 + 0] = s[l15 * 4 + r];
      sSc[(w * 32 + row) * 2 + 1] = s[8 + l15 * 4 + r];
    }
  }
  __syncthreads();  // also guarantees all sL reads (mega pass) are done
  // softmax + ctx combine (registers only), then write ctx over sL
#pragma unroll
  for (int m = 0; m < 2; ++m) {
    const int pw = w ^ 1;  // partner wave: other half of this head
#pragma unroll
    for (int r = 0; r < 4; ++r) {
      const int row = m * 16 + kg4 * 4 + r;
      const float t0 = s[m * 4 + r] + sSc[(pw * 32 + row) * 2 + 0];
      const float t1 = s[8 + m * 4 + r] + sSc[(pw * 32 + row) * 2 + 1];
      const float a1 = 1.0f / (1.0f + expf((t0 - t1) * 0.125f));  // scale = 1/sqrt(64)
      const float a0 = 1.0f - a1;
#pragma unroll
      for (int n = 0; n < 2; ++n) {
        const float bv = bin[512 + (f0 + n) * 16 + l15];  // a0+a1=1 folds v bias
        stC(sL, row, (f0 + n) * 16 + l15, a0 * vg[m][n][r] + a1 * vl[m][n][r] + bv);
      }
    }
  }
  __syncthreads();

  // ---- phase 3: out-proj + residual; x written IN-PLACE over g in sG
  {
    f32x4 at[2][2];
#pragma unroll
    for (int m = 0; m < 2; ++m) { at[m][0] = fzero4(); at[m][1] = fzero4(); }
    gemm256(sL, wsw + WO_OFF, f0, at, lane);
    float st[16];
#pragma unroll
    for (int i = 0; i < 16; ++i) st[i] = 0.f;
#pragma unroll
    for (int n = 0; n < 2; ++n) {
      const int col = (f0 + n) * 16 + l15;
      const float bv = bout[col];
#pragma unroll
      for (int m = 0; m < 2; ++m)
#pragma unroll
        for (int r = 0; r < 4; ++r) {
          const int row = m * 16 + kg4 * 4 + r;
          const float x = at[m][n][r] + bv + ldC(sG, row, col);
          stC(sG, row, col, x);  // x overwrites g (same element, same wave)
          st[m * 4 + r] += x;
          st[8 + m * 4 + r] += x * x;
        }
    }
    red16<16>(st);
    if (l15 < 2) {
#pragma unroll
      for (int r = 0; r < 4; ++r) {
        const int row = l15 * 16 + kg4 * 4 + r;
        sLN[(w * 32 + row) * 2 + 0] = st[l15 * 4 + r];
        sLN[(w * 32 + row) * 2 + 1] = st[8 + l15 * 4 + r];
      }
    }
  }
  __syncthreads();
  if (tid < 64) {
    const int row = tid >> 1, j = tid & 1;
    float v = 0.f;
#pragma unroll
    for (int ww = 0; ww < 8; ++ww) v += sLN[(ww * 32 + row) * 2 + j];
    sMu[row * 2 + j] = v;
  }
  __syncthreads();
  // normalize: read x from sG, write y back to the same slot
#pragma unroll
  for (int n = 0; n < 2; ++n) {
    const int col = (f0 + n) * 16 + l15;
    const float ga = gamma[col], be = beta[col];
#pragma unroll
    for (int m = 0; m < 2; ++m)
#pragma unroll
      for (int r = 0; r < 4; ++r) {
        const int row = m * 16 + kg4 * 4 + r;
        const float m_ = sMu[row * 2 + 0] * (1.0f / 256.0f);
        const float var = sMu[row * 2 + 1] * (1.0f / 256.0f) - m_ * m_;
        const float x = ldC(sG, row, col);
        stC(sG, row, col, (x - m_) * rsqrtf(var + 1e-5f) * ga + be);
      }
  }
  __syncthreads();

  // ---- phase 4: MLP head (y lives in sG; wave w owns hidden cols [16w, 16w+16))
  f32x4 ha[2];
  ha[0] = fzero4();
  ha[1] = fzero4();
#pragma unroll 2
  for (int kt = 0; kt < 8; ++kt) {
    bf16x8 b = ldB(wsw + W1_OFF, kt * 8 + w, lane);
    const int kb = kt * 64 + kg4 * 16;
#pragma unroll
    for (int m = 0; m < 2; ++m) {
      bf16x8 a = ldA<512>(sG, m * 16 + l15, kb);
      ha[m] = mfma16(a, b, ha[m]);
    }
  }
  {
    const int colh = w * 16 + l15;
    const float bv1 = b1[colh], w2v = W2[colh];
    float o[8];
#pragma unroll
    for (int m = 0; m < 2; ++m)
#pragma unroll
      for (int r = 0; r < 4; ++r) {
        float hv = ha[m][r] + bv1;
        hv = 0.5f * hv * (1.0f + erff(hv * 0.70710678118654752f));
        o[m * 4 + r] = hv * w2v;
      }
    red16<8>(o);
    if (l15 < 2) {
#pragma unroll
      for (int r = 0; r < 4; ++r)
        sPO[w * 32 + l15 * 16 + kg4 * 4 + r] = o[l15 * 4 + r];
    }
  }
  __syncthreads();
  if (tid < 32) {
    float acc = b2[0];
#pragma unroll
    for (int ww = 0; ww < 8; ++ww) acc += sPO[ww * 32 + tid];
    out[(size_t)blk * 32 + tid] = acc;
  }
}

extern "C" void kernel_launch(void* const* d_in, const int* in_sizes, int n_in,
                              void* d_out, int out_size, void* d_ws, size_t ws_size,
                              hipStream_t stream) {
  (void)in_sizes; (void)n_in; (void)out_size; (void)ws_size;
  const float* gdiff = (const float*)d_in[0];
  const float* ldiff = (const float*)d_in[1];
  const float* Wg    = (const float*)d_in[2];
  const float* bg    = (const float*)d_in[3];
  const float* Wl    = (const float*)d_in[4];
  const float* bl    = (const float*)d_in[5];
  const float* Win   = (const float*)d_in[6];
  const float* bin   = (const float*)d_in[7];
  const float* Wout  = (const float*)d_in[8];
  const float* bout  = (const float*)d_in[9];
  const float* gamma = (const float*)d_in[10];
  const float* beta  = (const float*)d_in[11];
  const float* W1    = (const float*)d_in[12];
  const float* b1    = (const float*)d_in[13];
  const float* W2    = (const float*)d_in[14];
  const float* b2    = (const float*)d_in[15];
  unsigned short* ws = (unsigned short*)d_ws;
  float* out = (float*)d_out;

  convert_w<<<dim3((W_TOTAL + 255) / 256), dim3(256), 0, stream>>>(Wg, Wl, Win, Wout, W1, ws);
  dca_fused<<<dim3(2048), dim3(512), 0, stream>>>(gdiff, ldiff, bg, bl, bin, bout, gamma,
                                                  beta, b1, W2, b2,
                                                  (const unsigned short*)ws, out);
}

// Round 16
// 211.050 us; speedup vs baseline: 1.0219x; 1.0219x over previous
//
#include <hip/hip_runtime.h>
#include <math.h>

typedef __attribute__((ext_vector_type(4))) float f32x4;
typedef __attribute__((ext_vector_type(8))) __bf16 bf16x8;

static constexpr int WG_OFF = 0;
static constexpr int WL_OFF = 163840;
static constexpr int WQ_OFF = 327680;
static constexpr int WK_OFF = 393216;
static constexpr int WV_OFF = 458752;
static constexpr int WO_OFF = 524288;
static constexpr int W1_OFF = 589824;
static constexpr int W_TOTAL = 622592;

__device__ __forceinline__ unsigned short f2bf(float f) {
  unsigned u = __builtin_bit_cast(unsigned, f);
  u += 0x7FFFu + ((u >> 16) & 1u);
  return (unsigned short)(u >> 16);
}

__device__ __forceinline__ f32x4 mfma16(bf16x8 a, bf16x8 b, f32x4 c) {
  return __builtin_amdgcn_mfma_f32_16x16x32_bf16(a, b, c, 0, 0, 0);
}
__device__ __forceinline__ f32x4 fzero4() {
  f32x4 v; v[0] = 0.f; v[1] = 0.f; v[2] = 0.f; v[3] = 0.f; return v;
}

// B fragment: frag-major layout in ws; one coalesced 1KB wave-read from global (L2).
__device__ __forceinline__ bf16x8 ldB(const unsigned short* __restrict__ ws, int fragIdx, int lane) {
  return *(const bf16x8*)(ws + (size_t)(fragIdx * 64 + lane) * 8);
}

// A-frag (16 rows x 32 k) from XOR-swizzled LDS tile with row byte-stride STRIDE.
template <int STRIDE>
__device__ __forceinline__ bf16x8 ldA(const char* s, int row, int kbyte) {
  return *(const bf16x8*)(s + row * STRIDE + (kbyte ^ ((row & 7) << 4)));
}

__device__ __forceinline__ void stC(char* s, int row, int col, float v) {
  *(__bf16*)(s + row * 512 + ((col * 2) ^ ((row & 7) << 4))) = (__bf16)v;
}
__device__ __forceinline__ float ldC(const char* s, int row, int col) {
  return (float)*(const __bf16*)(s + row * 512 + ((col * 2) ^ ((row & 7) << 4)));
}

__device__ __forceinline__ bf16x8 cvt8(float4 a, float4 b) {
  bf16x8 t;
  t[0] = (__bf16)a.x; t[1] = (__bf16)a.y; t[2] = (__bf16)a.z; t[3] = (__bf16)a.w;
  t[4] = (__bf16)b.x; t[5] = (__bf16)b.y; t[6] = (__bf16)b.z; t[7] = (__bf16)b.w;
  return t;
}

template <int N>
__device__ __forceinline__ void red16(float* v) {
#pragma unroll
  for (int m = 1; m < 16; m <<= 1) {
#pragma unroll
    for (int i = 0; i < N; ++i) v[i] += __shfl_xor(v[i], m);
  }
}

// stage [32 rows][640] fp32 -> bf16 swizzled LDS (row stride 1280B)
__device__ __forceinline__ void stageA32(const float* __restrict__ A, char* sA, int tid) {
#pragma unroll
  for (int i = 0; i < 5; ++i) {
    const int idx = i * 512 + tid;
    const int row = idx / 80;
    const int c8 = idx - row * 80;
    const float* ap = A + (size_t)idx * 8;
    float4 f0 = *(const float4*)ap;
    float4 f1 = *(const float4*)(ap + 4);
    *(bf16x8*)(sA + row * 1280 + ((c8 * 16) ^ ((row & 7) << 4))) = cvt8(f0, f1);
  }
}

// proj: [32 rows x 640] @ W -> wave's 2 col-frags; unroll capped at 2.
__device__ __forceinline__ void proj640(const char* sA, const unsigned short* __restrict__ wsW,
                                        const float* __restrict__ bias, char* sDst,
                                        int f0, int lane) {
  const int l15 = lane & 15, kg4 = lane >> 4;
  f32x4 acc[2][2];
#pragma unroll
  for (int m = 0; m < 2; ++m)
#pragma unroll
    for (int n = 0; n < 2; ++n) acc[m][n] = fzero4();
#pragma unroll 2
  for (int kt = 0; kt < 20; ++kt) {
    bf16x8 b0 = ldB(wsW, kt * 16 + f0, lane);
    bf16x8 b1 = ldB(wsW, kt * 16 + f0 + 1, lane);
    const int kb = kt * 64 + kg4 * 16;
    __builtin_amdgcn_s_setprio(1);
#pragma unroll
    for (int m = 0; m < 2; ++m) {
      bf16x8 a = ldA<1280>(sA, m * 16 + l15, kb);
      acc[m][0] = mfma16(a, b0, acc[m][0]);
      acc[m][1] = mfma16(a, b1, acc[m][1]);
    }
    __builtin_amdgcn_s_setprio(0);
  }
#pragma unroll
  for (int n = 0; n < 2; ++n) {
    const int col = (f0 + n) * 16 + l15;
    const float bv = bias[col];
#pragma unroll
    for (int m = 0; m < 2; ++m)
#pragma unroll
      for (int r = 0; r < 4; ++r)
        stC(sDst, m * 16 + kg4 * 4 + r, col, acc[m][n][r] + bv);
  }
}

// K=256 gemm, wave's 2 col-frags; unroll capped at 2 (bounds B-load hoisting).
__device__ __forceinline__ void gemm256(const char* sA, const unsigned short* __restrict__ wsW,
                                        int f0, f32x4 (&acc)[2][2], int lane) {
  const int l15 = lane & 15, kg4 = lane >> 4;
#pragma unroll 2
  for (int kt = 0; kt < 8; ++kt) {
    bf16x8 b0 = ldB(wsW, kt * 16 + f0, lane);
    bf16x8 b1 = ldB(wsW, kt * 16 + f0 + 1, lane);
    const int kb = kt * 64 + kg4 * 16;
    __builtin_amdgcn_s_setprio(1);
#pragma unroll
    for (int m = 0; m < 2; ++m) {
      bf16x8 a = ldA<512>(sA, m * 16 + l15, kb);
      acc[m][0] = mfma16(a, b0, acc[m][0]);
      acc[m][1] = mfma16(a, b1, acc[m][1]);
    }
    __builtin_amdgcn_s_setprio(0);
  }
}

// Dual-A K=256 gemm: one B-load feeds 4 MFMAs (g-tile and l-tile); unroll 2.
__device__ __forceinline__ void gemm256d(const char* sG, const char* sL,
                                         const unsigned short* __restrict__ wsW, int f0,
                                         f32x4 (&ag)[2][2], f32x4 (&al)[2][2], int lane) {
  const int l15 = lane & 15, kg4 = lane >> 4;
#pragma unroll 2
  for (int kt = 0; kt < 8; ++kt) {
    bf16x8 b0 = ldB(wsW, kt * 16 + f0, lane);
    bf16x8 b1 = ldB(wsW, kt * 16 + f0 + 1, lane);
    const int kb = kt * 64 + kg4 * 16;
    __builtin_amdgcn_s_setprio(1);
#pragma unroll
    for (int m = 0; m < 2; ++m) {
      bf16x8 g = ldA<512>(sG, m * 16 + l15, kb);
      bf16x8 l = ldA<512>(sL, m * 16 + l15, kb);
      ag[m][0] = mfma16(g, b0, ag[m][0]);
      ag[m][1] = mfma16(g, b1, ag[m][1]);
      al[m][0] = mfma16(l, b0, al[m][0]);
      al[m][1] = mfma16(l, b1, al[m][1]);
    }
    __builtin_amdgcn_s_setprio(0);
  }
}

__global__ void convert_w(const float* __restrict__ Wg, const float* __restrict__ Wl,
                          const float* __restrict__ Win, const float* __restrict__ Wout,
                          const float* __restrict__ W1, unsigned short* __restrict__ ws) {
  const int tid = blockIdx.x * 256 + threadIdx.x;
  if (tid >= W_TOTAL) return;
  const float* src;
  int stride, coloff, base, lognf;
  if (tid < WL_OFF)      { src = Wg;   stride = 256; coloff = 0;   base = WG_OFF; lognf = 4; }
  else if (tid < WQ_OFF) { src = Wl;   stride = 256; coloff = 0;   base = WL_OFF; lognf = 4; }
  else if (tid < WK_OFF) { src = Win;  stride = 768; coloff = 0;   base = WQ_OFF; lognf = 4; }
  else if (tid < WV_OFF) { src = Win;  stride = 768; coloff = 256; base = WK_OFF; lognf = 4; }
  else if (tid < WO_OFF) { src = Win;  stride = 768; coloff = 512; base = WV_OFF; lognf = 4; }
  else if (tid < W1_OFF) { src = Wout; stride = 256; coloff = 0;   base = WO_OFF; lognf = 4; }
  else                   { src = W1;   stride = 128; coloff = 0;   base = W1_OFF; lognf = 3; }
  const int idx = tid - base;
  const int j = idx & 7;
  const int lane = (idx >> 3) & 63;
  const int fl = idx >> 9;
  const int n = fl & ((1 << lognf) - 1);
  const int kt = fl >> lognf;
  const int k = kt * 32 + (lane >> 4) * 8 + j;
  const int col = coloff + n * 16 + (lane & 15);
  ws[tid] = f2bf(src[k * stride + col]);
}

__global__ __launch_bounds__(512)
__attribute__((amdgpu_waves_per_eu(4, 4)))  // 128 unified regs/wave; 2 blocks/CU (LDS-capped)
void dca_fused(
    const float* __restrict__ gdiff, const float* __restrict__ ldiff,
    const float* __restrict__ bg, const float* __restrict__ bl,
    const float* __restrict__ bin, const float* __restrict__ bout,
    const float* __restrict__ gamma, const float* __restrict__ beta,
    const float* __restrict__ b1, const float* __restrict__ W2,
    const float* __restrict__ b2, const unsigned short* __restrict__ wsw,
    float* __restrict__ out) {
  __shared__ __align__(16) char sMem[73728];
  char* sA = sMem;                      // [32][1280B] staged A (40960 B)
  char* sG = sMem + 40960;              // [32][512B] g tile -> x -> y
  char* sL = sMem + 57344;              // [32][512B] l tile -> ctx
  float* sSc = (float*)sMem;            // [8][32][2] score partials (aliases dead sA)
  float* sLN = (float*)(sMem + 2048);   // [8][32][2] LN partials
  float* sMu = (float*)(sMem + 4096);   // [32][2]
  float* sPO = (float*)(sMem + 4352);   // [8][32]

  const int tid = threadIdx.x;
  const int blk = blockIdx.x;
  const int lane = tid & 63, l15 = lane & 15, kg4 = lane >> 4;
  const int w = tid >> 6;
  const int f0 = w * 2;

  // ---- phase 1: stage g -> proj g ; stage l -> proj l
  stageA32(gdiff + (size_t)blk * 32 * 640, sA, tid);
  __syncthreads();
  proj640(sA, wsw + WG_OFF, bg, sG, f0, lane);
  __syncthreads();
  stageA32(ldiff + (size_t)blk * 32 * 640, sA, tid);
  __syncthreads();
  proj640(sA, wsw + WL_OFF, bl, sL, f0, lane);
  __syncthreads();

  // ---- phase 2: MERGED q + kg + kl triple pass (g A-frag shared by q and kg).
  f32x4 q[2][2], kg[2][2], kl[2][2];
#pragma unroll
  for (int m = 0; m < 2; ++m)
#pragma unroll
    for (int n = 0; n < 2; ++n) { q[m][n] = fzero4(); kg[m][n] = fzero4(); kl[m][n] = fzero4(); }
#pragma unroll 1
  for (int kt = 0; kt < 8; ++kt) {
    bf16x8 bq0 = ldB(wsw + WQ_OFF, kt * 16 + f0, lane);
    bf16x8 bq1 = ldB(wsw + WQ_OFF, kt * 16 + f0 + 1, lane);
    bf16x8 bk0 = ldB(wsw + WK_OFF, kt * 16 + f0, lane);
    bf16x8 bk1 = ldB(wsw + WK_OFF, kt * 16 + f0 + 1, lane);
    const int kb = kt * 64 + kg4 * 16;
    __builtin_amdgcn_s_setprio(1);
#pragma unroll
    for (int m = 0; m < 2; ++m) {
      bf16x8 g = ldA<512>(sG, m * 16 + l15, kb);
      bf16x8 l = ldA<512>(sL, m * 16 + l15, kb);
      q[m][0] = mfma16(g, bq0, q[m][0]);
      q[m][1] = mfma16(g, bq1, q[m][1]);
      kg[m][0] = mfma16(g, bk0, kg[m][0]);
      kg[m][1] = mfma16(g, bk1, kg[m][1]);
      kl[m][0] = mfma16(l, bk0, kl[m][0]);
      kl[m][1] = mfma16(l, bk1, kl[m][1]);
    }
    __builtin_amdgcn_s_setprio(0);
  }
  // scores: q gets its bias (k bias cancels in s0-s1); dot over the wave's 2 col-frags
  float s[16];
#pragma unroll
  for (int m = 0; m < 2; ++m) {
#pragma unroll
    for (int r = 0; r < 4; ++r) {
      float t0 = 0.f, t1 = 0.f;
#pragma unroll
      for (int n = 0; n < 2; ++n) {
        const float qv = q[m][n][r] + bin[(f0 + n) * 16 + l15];
        t0 += qv * kg[m][n][r];
        t1 += qv * kl[m][n][r];
      }
      s[m * 4 + r] = t0;
      s[8 + m * 4 + r] = t1;
    }
  }
  red16<16>(s);
  if (l15 < 2) {
#pragma unroll
    for (int r = 0; r < 4; ++r) {
      const int row = l15 * 16 + kg4 * 4 + r;
      sSc[(w * 32 + row) * 2 + 0] = s[l15 * 4 + r];
      sSc[(w * 32 + row) * 2 + 1] = s[8 + l15 * 4 + r];
    }
  }
  __syncthreads();
  float a1v[2][4];
  {
    const int pw = w ^ 1;  // partner wave: other half of this head
#pragma unroll
    for (int m = 0; m < 2; ++m)
#pragma unroll
      for (int r = 0; r < 4; ++r) {
        const int row = m * 16 + kg4 * 4 + r;
        const float t0 = s[m * 4 + r] + sSc[(pw * 32 + row) * 2 + 0];
        const float t1 = s[8 + m * 4 + r] + sSc[(pw * 32 + row) * 2 + 1];
        a1v[m][r] = 1.0f / (1.0f + expf((t0 - t1) * 0.125f));  // scale = 1/sqrt(64)
      }
  }

  // v: ONE dual-A pass (vg+vl), fold into ctx
  f32x4 ctx[2][2];
  {
    f32x4 vg[2][2], vl[2][2];
#pragma unroll
    for (int m = 0; m < 2; ++m) {
      vg[m][0] = fzero4(); vg[m][1] = fzero4();
      vl[m][0] = fzero4(); vl[m][1] = fzero4();
    }
    gemm256d(sG, sL, wsw + WV_OFF, f0, vg, vl, lane);
#pragma unroll
    for (int n = 0; n < 2; ++n) {
      const float bv = bin[512 + (f0 + n) * 16 + l15];  // a0+a1=1 folds v bias
#pragma unroll
      for (int m = 0; m < 2; ++m)
#pragma unroll
        for (int r = 0; r < 4; ++r)
          ctx[m][n][r] = (1.0f - a1v[m][r]) * vg[m][n][r] + a1v[m][r] * vl[m][n][r] + bv;
    }
  }
  __syncthreads();  // all waves done reading sL
#pragma unroll
  for (int n = 0; n < 2; ++n) {
    const int col = (f0 + n) * 16 + l15;
#pragma unroll
    for (int m = 0; m < 2; ++m)
#pragma unroll
      for (int r = 0; r < 4; ++r)
        stC(sL, m * 16 + kg4 * 4 + r, col, ctx[m][n][r]);
  }
  __syncthreads();

  // ---- phase 3: out-proj + residual; x written IN-PLACE over g in sG
  {
    f32x4 at[2][2];
#pragma unroll
    for (int m = 0; m < 2; ++m) { at[m][0] = fzero4(); at[m][1] = fzero4(); }
    gemm256(sL, wsw + WO_OFF, f0, at, lane);
    float st[16];
#pragma unroll
    for (int i = 0; i < 16; ++i) st[i] = 0.f;
#pragma unroll
    for (int n = 0; n < 2; ++n) {
      const int col = (f0 + n) * 16 + l15;
      const float bv = bout[col];
#pragma unroll
      for (int m = 0; m < 2; ++m)
#pragma unroll
        for (int r = 0; r < 4; ++r) {
          const int row = m * 16 + kg4 * 4 + r;
          const float x = at[m][n][r] + bv + ldC(sG, row, col);
          stC(sG, row, col, x);  // x overwrites g (same element, same wave)
          st[m * 4 + r] += x;
          st[8 + m * 4 + r] += x * x;
        }
    }
    red16<16>(st);
    if (l15 < 2) {
#pragma unroll
      for (int r = 0; r < 4; ++r) {
        const int row = l15 * 16 + kg4 * 4 + r;
        sLN[(w * 32 + row) * 2 + 0] = st[l15 * 4 + r];
        sLN[(w * 32 + row) * 2 + 1] = st[8 + l15 * 4 + r];
      }
    }
  }
  __syncthreads();
  if (tid < 64) {
    const int row = tid >> 1, j = tid & 1;
    float v = 0.f;
#pragma unroll
    for (int ww = 0; ww < 8; ++ww) v += sLN[(ww * 32 + row) * 2 + j];
    sMu[row * 2 + j] = v;
  }
  __syncthreads();
  // normalize: read x from sG, write y back to the same slot
#pragma unroll
  for (int n = 0; n < 2; ++n) {
    const int col = (f0 + n) * 16 + l15;
    const float ga = gamma[col], be = beta[col];
#pragma unroll
    for (int m = 0; m < 2; ++m)
#pragma unroll
      for (int r = 0; r < 4; ++r) {
        const int row = m * 16 + kg4 * 4 + r;
        const float m_ = sMu[row * 2 + 0] * (1.0f / 256.0f);
        const float var = sMu[row * 2 + 1] * (1.0f / 256.0f) - m_ * m_;
        const float x = ldC(sG, row, col);
        stC(sG, row, col, (x - m_) * rsqrtf(var + 1e-5f) * ga + be);
      }
  }
  __syncthreads();

  // ---- phase 4: MLP head (y lives in sG; wave w owns hidden cols [16w, 16w+16))
  f32x4 ha[2];
  ha[0] = fzero4();
  ha[1] = fzero4();
#pragma unroll 2
  for (int kt = 0; kt < 8; ++kt) {
    bf16x8 b = ldB(wsw + W1_OFF, kt * 8 + w, lane);
    const int kb = kt * 64 + kg4 * 16;
    __builtin_amdgcn_s_setprio(1);
#pragma unroll
    for (int m = 0; m < 2; ++m) {
      bf16x8 a = ldA<512>(sG, m * 16 + l15, kb);
      ha[m] = mfma16(a, b, ha[m]);
    }
    __builtin_amdgcn_s_setprio(0);
  }
  {
    const int colh = w * 16 + l15;
    const float bv1 = b1[colh], w2v = W2[colh];
    float o[8];
#pragma unroll
    for (int m = 0; m < 2; ++m)
#pragma unroll
      for (int r = 0; r < 4; ++r) {
        float hv = ha[m][r] + bv1;
        hv = 0.5f * hv * (1.0f + erff(hv * 0.70710678118654752f));
        o[m * 4 + r] = hv * w2v;
      }
    red16<8>(o);
    if (l15 < 2) {
#pragma unroll
      for (int r = 0; r < 4; ++r)
        sPO[w * 32 + l15 * 16 + kg4 * 4 + r] = o[l15 * 4 + r];
    }
  }
  __syncthreads();
  if (tid < 32) {
    float acc = b2[0];
#pragma unroll
    for (int ww = 0; ww < 8; ++ww) acc += sPO[ww * 32 + tid];
    out[(size_t)blk * 32 + tid] = acc;
  }
}

extern "C" void kernel_launch(void* const* d_in, const int* in_sizes, int n_in,
                              void* d_out, int out_size, void* d_ws, size_t ws_size,
                              hipStream_t stream) {
  (void)in_sizes; (void)n_in; (void)out_size; (void)ws_size;
  const float* gdiff = (const float*)d_in[0];
  const float* ldiff = (const float*)d_in[1];
  const float* Wg    = (const float*)d_in[2];
  const float* bg    = (const float*)d_in[3];
  const float* Wl    = (const float*)d_in[4];
  const float* bl    = (const float*)d_in[5];
  const float* Win   = (const float*)d_in[6];
  const float* bin   = (const float*)d_in[7];
  const float* Wout  = (const float*)d_in[8];
  const float* bout  = (const float*)d_in[9];
  const float* gamma = (const float*)d_in[10];
  const float* beta  = (const float*)d_in[11];
  const float* W1    = (const float*)d_in[12];
  const float* b1    = (const float*)d_in[13];
  const float* W2    = (const float*)d_in[14];
  const float* b2    = (const float*)d_in[15];
  unsigned short* ws = (unsigned short*)d_ws;
  float* out = (float*)d_out;

  convert_w<<<dim3((W_TOTAL + 255) / 256), dim3(256), 0, stream>>>(Wg, Wl, Win, Wout, W1, ws);
  dca_fused<<<dim3(2048), dim3(512), 0, stream>>>(gdiff, ldiff, bg, bl, bin, bout, gamma,
                                                  beta, b1, W2, b2,
                                                  (const unsigned short*)ws, out);
}

// Round 17
// 205.152 us; speedup vs baseline: 1.0513x; 1.0288x over previous
//
#include <hip/hip_runtime.h>
#include <math.h>

typedef __attribute__((ext_vector_type(4))) float f32x4;
typedef __attribute__((ext_vector_type(8))) __bf16 bf16x8;

static constexpr int WG_OFF = 0;
static constexpr int WL_OFF = 163840;
static constexpr int WQ_OFF = 327680;
static constexpr int WK_OFF = 393216;
static constexpr int WV_OFF = 458752;
static constexpr int WO_OFF = 524288;
static constexpr int W1_OFF = 589824;
static constexpr int W_TOTAL = 622592;

__device__ __forceinline__ unsigned short f2bf(float f) {
  unsigned u = __builtin_bit_cast(unsigned, f);
  u += 0x7FFFu + ((u >> 16) & 1u);
  return (unsigned short)(u >> 16);
}

__device__ __forceinline__ f32x4 mfma16(bf16x8 a, bf16x8 b, f32x4 c) {
  return __builtin_amdgcn_mfma_f32_16x16x32_bf16(a, b, c, 0, 0, 0);
}
__device__ __forceinline__ f32x4 fzero4() {
  f32x4 v; v[0] = 0.f; v[1] = 0.f; v[2] = 0.f; v[3] = 0.f; return v;
}

// B fragment: frag-major layout in ws; one coalesced 1KB wave-read from global (L2).
__device__ __forceinline__ bf16x8 ldB(const unsigned short* __restrict__ ws, int fragIdx, int lane) {
  return *(const bf16x8*)(ws + (size_t)(fragIdx * 64 + lane) * 8);
}

// A-frag (16 rows x 32 k) from XOR-swizzled LDS tile with row byte-stride STRIDE.
template <int STRIDE>
__device__ __forceinline__ bf16x8 ldA(const char* s, int row, int kbyte) {
  return *(const bf16x8*)(s + row * STRIDE + (kbyte ^ ((row & 7) << 4)));
}

__device__ __forceinline__ void stC(char* s, int row, int col, float v) {
  *(__bf16*)(s + row * 512 + ((col * 2) ^ ((row & 7) << 4))) = (__bf16)v;
}
__device__ __forceinline__ float ldC(const char* s, int row, int col) {
  return (float)*(const __bf16*)(s + row * 512 + ((col * 2) ^ ((row & 7) << 4)));
}

__device__ __forceinline__ bf16x8 cvt8(float4 a, float4 b) {
  bf16x8 t;
  t[0] = (__bf16)a.x; t[1] = (__bf16)a.y; t[2] = (__bf16)a.z; t[3] = (__bf16)a.w;
  t[4] = (__bf16)b.x; t[5] = (__bf16)b.y; t[6] = (__bf16)b.z; t[7] = (__bf16)b.w;
  return t;
}

template <int N>
__device__ __forceinline__ void red16(float* v) {
#pragma unroll
  for (int m = 1; m < 16; m <<= 1) {
#pragma unroll
    for (int i = 0; i < N; ++i) v[i] += __shfl_xor(v[i], m);
  }
}

// stage [32 rows][640] fp32 -> bf16 swizzled LDS (row stride 1280B)
__device__ __forceinline__ void stageA32(const float* __restrict__ A, char* sA, int tid) {
#pragma unroll
  for (int i = 0; i < 5; ++i) {
    const int idx = i * 512 + tid;
    const int row = idx / 80;
    const int c8 = idx - row * 80;
    const float* ap = A + (size_t)idx * 8;
    float4 f0 = *(const float4*)ap;
    float4 f1 = *(const float4*)(ap + 4);
    *(bf16x8*)(sA + row * 1280 + ((c8 * 16) ^ ((row & 7) << 4))) = cvt8(f0, f1);
  }
}

// proj: [32 rows x 640] @ W -> wave's 2 col-frags; unroll capped at 2.
__device__ __forceinline__ void proj640(const char* sA, const unsigned short* __restrict__ wsW,
                                        const float* __restrict__ bias, char* sDst,
                                        int f0, int lane) {
  const int l15 = lane & 15, kg4 = lane >> 4;
  f32x4 acc[2][2];
#pragma unroll
  for (int m = 0; m < 2; ++m)
#pragma unroll
    for (int n = 0; n < 2; ++n) acc[m][n] = fzero4();
#pragma unroll 2
  for (int kt = 0; kt < 20; ++kt) {
    bf16x8 b0 = ldB(wsW, kt * 16 + f0, lane);
    bf16x8 b1 = ldB(wsW, kt * 16 + f0 + 1, lane);
    const int kb = kt * 64 + kg4 * 16;
#pragma unroll
    for (int m = 0; m < 2; ++m) {
      bf16x8 a = ldA<1280>(sA, m * 16 + l15, kb);
      acc[m][0] = mfma16(a, b0, acc[m][0]);
      acc[m][1] = mfma16(a, b1, acc[m][1]);
    }
  }
#pragma unroll
  for (int n = 0; n < 2; ++n) {
    const int col = (f0 + n) * 16 + l15;
    const float bv = bias[col];
#pragma unroll
    for (int m = 0; m < 2; ++m)
#pragma unroll
      for (int r = 0; r < 4; ++r)
        stC(sDst, m * 16 + kg4 * 4 + r, col, acc[m][n][r] + bv);
  }
}

// K=256 gemm, wave's 2 col-frags; unroll capped at 2 (bounds B-load hoisting).
__device__ __forceinline__ void gemm256(const char* sA, const unsigned short* __restrict__ wsW,
                                        int f0, f32x4 (&acc)[2][2], int lane) {
  const int l15 = lane & 15, kg4 = lane >> 4;
#pragma unroll 2
  for (int kt = 0; kt < 8; ++kt) {
    bf16x8 b0 = ldB(wsW, kt * 16 + f0, lane);
    bf16x8 b1 = ldB(wsW, kt * 16 + f0 + 1, lane);
    const int kb = kt * 64 + kg4 * 16;
#pragma unroll
    for (int m = 0; m < 2; ++m) {
      bf16x8 a = ldA<512>(sA, m * 16 + l15, kb);
      acc[m][0] = mfma16(a, b0, acc[m][0]);
      acc[m][1] = mfma16(a, b1, acc[m][1]);
    }
  }
}

// Dual-A K=256 gemm: one B-load feeds 4 MFMAs (g-tile and l-tile); unroll 2.
__device__ __forceinline__ void gemm256d(const char* sG, const char* sL,
                                         const unsigned short* __restrict__ wsW, int f0,
                                         f32x4 (&ag)[2][2], f32x4 (&al)[2][2], int lane) {
  const int l15 = lane & 15, kg4 = lane >> 4;
#pragma unroll 2
  for (int kt = 0; kt < 8; ++kt) {
    bf16x8 b0 = ldB(wsW, kt * 16 + f0, lane);
    bf16x8 b1 = ldB(wsW, kt * 16 + f0 + 1, lane);
    const int kb = kt * 64 + kg4 * 16;
#pragma unroll
    for (int m = 0; m < 2; ++m) {
      bf16x8 g = ldA<512>(sG, m * 16 + l15, kb);
      bf16x8 l = ldA<512>(sL, m * 16 + l15, kb);
      ag[m][0] = mfma16(g, b0, ag[m][0]);
      ag[m][1] = mfma16(g, b1, ag[m][1]);
      al[m][0] = mfma16(l, b0, al[m][0]);
      al[m][1] = mfma16(l, b1, al[m][1]);
    }
  }
}

__global__ void convert_w(const float* __restrict__ Wg, const float* __restrict__ Wl,
                          const float* __restrict__ Win, const float* __restrict__ Wout,
                          const float* __restrict__ W1, unsigned short* __restrict__ ws) {
  const int tid = blockIdx.x * 256 + threadIdx.x;
  if (tid >= W_TOTAL) return;
  const float* src;
  int stride, coloff, base, lognf;
  if (tid < WL_OFF)      { src = Wg;   stride = 256; coloff = 0;   base = WG_OFF; lognf = 4; }
  else if (tid < WQ_OFF) { src = Wl;   stride = 256; coloff = 0;   base = WL_OFF; lognf = 4; }
  else if (tid < WK_OFF) { src = Win;  stride = 768; coloff = 0;   base = WQ_OFF; lognf = 4; }
  else if (tid < WV_OFF) { src = Win;  stride = 768; coloff = 256; base = WK_OFF; lognf = 4; }
  else if (tid < WO_OFF) { src = Win;  stride = 768; coloff = 512; base = WV_OFF; lognf = 4; }
  else if (tid < W1_OFF) { src = Wout; stride = 256; coloff = 0;   base = WO_OFF; lognf = 4; }
  else                   { src = W1;   stride = 128; coloff = 0;   base = W1_OFF; lognf = 3; }
  const int idx = tid - base;
  const int j = idx & 7;
  const int lane = (idx >> 3) & 63;
  const int fl = idx >> 9;
  const int n = fl & ((1 << lognf) - 1);
  const int kt = fl >> lognf;
  const int k = kt * 32 + (lane >> 4) * 8 + j;
  const int col = coloff + n * 16 + (lane & 15);
  ws[tid] = f2bf(src[k * stride + col]);
}

__global__ __launch_bounds__(512)
__attribute__((amdgpu_waves_per_eu(4, 4)))  // 128 unified regs/wave; 2 blocks/CU (LDS-capped)
void dca_fused(
    const float* __restrict__ gdiff, const float* __restrict__ ldiff,
    const float* __restrict__ bg, const float* __restrict__ bl,
    const float* __restrict__ bin, const float* __restrict__ bout,
    const float* __restrict__ gamma, const float* __restrict__ beta,
    const float* __restrict__ b1, const float* __restrict__ W2,
    const float* __restrict__ b2, const unsigned short* __restrict__ wsw,
    float* __restrict__ out) {
  __shared__ __align__(16) char sMem[73728];
  char* sA = sMem;                      // [32][1280B] staged A (40960 B)
  char* sG = sMem + 40960;              // [32][512B] g tile -> x -> y
  char* sL = sMem + 57344;              // [32][512B] l tile -> ctx
  float* sSc = (float*)sMem;            // [8][32][2] score partials (aliases dead sA)
  float* sLN = (float*)(sMem + 2048);   // [8][32][2] LN partials
  float* sMu = (float*)(sMem + 4096);   // [32][2]
  float* sPO = (float*)(sMem + 4352);   // [8][32]

  const int tid = threadIdx.x;
  const int blk = blockIdx.x;
  const int lane = tid & 63, l15 = lane & 15, kg4 = lane >> 4;
  const int w = tid >> 6;
  const int f0 = w * 2;

  // ---- phase 1: stage g -> proj g ; stage l -> proj l
  stageA32(gdiff + (size_t)blk * 32 * 640, sA, tid);
  __syncthreads();
  proj640(sA, wsw + WG_OFF, bg, sG, f0, lane);
  __syncthreads();
  stageA32(ldiff + (size_t)blk * 32 * 640, sA, tid);
  __syncthreads();
  proj640(sA, wsw + WL_OFF, bl, sL, f0, lane);
  __syncthreads();

  // ---- phase 2: MERGED q + kg + kl triple pass (g A-frag shared by q and kg).
  f32x4 q[2][2], kg[2][2], kl[2][2];
#pragma unroll
  for (int m = 0; m < 2; ++m)
#pragma unroll
    for (int n = 0; n < 2; ++n) { q[m][n] = fzero4(); kg[m][n] = fzero4(); kl[m][n] = fzero4(); }
#pragma unroll 1
  for (int kt = 0; kt < 8; ++kt) {
    bf16x8 bq0 = ldB(wsw + WQ_OFF, kt * 16 + f0, lane);
    bf16x8 bq1 = ldB(wsw + WQ_OFF, kt * 16 + f0 + 1, lane);
    bf16x8 bk0 = ldB(wsw + WK_OFF, kt * 16 + f0, lane);
    bf16x8 bk1 = ldB(wsw + WK_OFF, kt * 16 + f0 + 1, lane);
    const int kb = kt * 64 + kg4 * 16;
#pragma unroll
    for (int m = 0; m < 2; ++m) {
      bf16x8 g = ldA<512>(sG, m * 16 + l15, kb);
      bf16x8 l = ldA<512>(sL, m * 16 + l15, kb);
      q[m][0] = mfma16(g, bq0, q[m][0]);
      q[m][1] = mfma16(g, bq1, q[m][1]);
      kg[m][0] = mfma16(g, bk0, kg[m][0]);
      kg[m][1] = mfma16(g, bk1, kg[m][1]);
      kl[m][0] = mfma16(l, bk0, kl[m][0]);
      kl[m][1] = mfma16(l, bk1, kl[m][1]);
    }
  }
  // scores: q gets its bias (k bias cancels in s0-s1); dot over the wave's 2 col-frags
  float s[16];
#pragma unroll
  for (int m = 0; m < 2; ++m) {
#pragma unroll
    for (int r = 0; r < 4; ++r) {
      float t0 = 0.f, t1 = 0.f;
#pragma unroll
      for (int n = 0; n < 2; ++n) {
        const float qv = q[m][n][r] + bin[(f0 + n) * 16 + l15];
        t0 += qv * kg[m][n][r];
        t1 += qv * kl[m][n][r];
      }
      s[m * 4 + r] = t0;
      s[8 + m * 4 + r] = t1;
    }
  }
  red16<16>(s);
  if (l15 < 2) {
#pragma unroll
    for (int r = 0; r < 4; ++r) {
      const int row = l15 * 16 + kg4 * 4 + r;
      sSc[(w * 32 + row) * 2 + 0] = s[l15 * 4 + r];
      sSc[(w * 32 + row) * 2 + 1] = s[8 + l15 * 4 + r];
    }
  }
  __syncthreads();
  float a1v[2][4];
  {
    const int pw = w ^ 1;  // partner wave: other half of this head
#pragma unroll
    for (int m = 0; m < 2; ++m)
#pragma unroll
      for (int r = 0; r < 4; ++r) {
        const int row = m * 16 + kg4 * 4 + r;
        const float t0 = s[m * 4 + r] + sSc[(pw * 32 + row) * 2 + 0];
        const float t1 = s[8 + m * 4 + r] + sSc[(pw * 32 + row) * 2 + 1];
        a1v[m][r] = 1.0f / (1.0f + expf((t0 - t1) * 0.125f));  // scale = 1/sqrt(64)
      }
  }

  // v: ONE dual-A pass (vg+vl), fold into ctx
  f32x4 ctx[2][2];
  {
    f32x4 vg[2][2], vl[2][2];
#pragma unroll
    for (int m = 0; m < 2; ++m) {
      vg[m][0] = fzero4(); vg[m][1] = fzero4();
      vl[m][0] = fzero4(); vl[m][1] = fzero4();
    }
    gemm256d(sG, sL, wsw + WV_OFF, f0, vg, vl, lane);
#pragma unroll
    for (int n = 0; n < 2; ++n) {
      const float bv = bin[512 + (f0 + n) * 16 + l15];  // a0+a1=1 folds v bias
#pragma unroll
      for (int m = 0; m < 2; ++m)
#pragma unroll
        for (int r = 0; r < 4; ++r)
          ctx[m][n][r] = (1.0f - a1v[m][r]) * vg[m][n][r] + a1v[m][r] * vl[m][n][r] + bv;
    }
  }
  __syncthreads();  // all waves done reading sL
#pragma unroll
  for (int n = 0; n < 2; ++n) {
    const int col = (f0 + n) * 16 + l15;
#pragma unroll
    for (int m = 0; m < 2; ++m)
#pragma unroll
      for (int r = 0; r < 4; ++r)
        stC(sL, m * 16 + kg4 * 4 + r, col, ctx[m][n][r]);
  }
  __syncthreads();

  // ---- phase 3: out-proj + residual; x written IN-PLACE over g in sG
  {
    f32x4 at[2][2];
#pragma unroll
    for (int m = 0; m < 2; ++m) { at[m][0] = fzero4(); at[m][1] = fzero4(); }
    gemm256(sL, wsw + WO_OFF, f0, at, lane);
    float st[16];
#pragma unroll
    for (int i = 0; i < 16; ++i) st[i] = 0.f;
#pragma unroll
    for (int n = 0; n < 2; ++n) {
      const int col = (f0 + n) * 16 + l15;
      const float bv = bout[col];
#pragma unroll
      for (int m = 0; m < 2; ++m)
#pragma unroll
        for (int r = 0; r < 4; ++r) {
          const int row = m * 16 + kg4 * 4 + r;
          const float x = at[m][n][r] + bv + ldC(sG, row, col);
          stC(sG, row, col, x);  // x overwrites g (same element, same wave)
          st[m * 4 + r] += x;
          st[8 + m * 4 + r] += x * x;
        }
    }
    red16<16>(st);
    if (l15 < 2) {
#pragma unroll
      for (int r = 0; r < 4; ++r) {
        const int row = l15 * 16 + kg4 * 4 + r;
        sLN[(w * 32 + row) * 2 + 0] = st[l15 * 4 + r];
        sLN[(w * 32 + row) * 2 + 1] = st[8 + l15 * 4 + r];
      }
    }
  }
  __syncthreads();
  if (tid < 64) {
    const int row = tid >> 1, j = tid & 1;
    float v = 0.f;
#pragma unroll
    for (int ww = 0; ww < 8; ++ww) v += sLN[(ww * 32 + row) * 2 + j];
    sMu[row * 2 + j] = v;
  }
  __syncthreads();
  // normalize: read x from sG, write y back to the same slot
#pragma unroll
  for (int n = 0; n < 2; ++n) {
    const int col = (f0 + n) * 16 + l15;
    const float ga = gamma[col], be = beta[col];
#pragma unroll
    for (int m = 0; m < 2; ++m)
#pragma unroll
      for (int r = 0; r < 4; ++r) {
        const int row = m * 16 + kg4 * 4 + r;
        const float m_ = sMu[row * 2 + 0] * (1.0f / 256.0f);
        const float var = sMu[row * 2 + 1] * (1.0f / 256.0f) - m_ * m_;
        const float x = ldC(sG, row, col);
        stC(sG, row, col, (x - m_) * rsqrtf(var + 1e-5f) * ga + be);
      }
  }
  __syncthreads();

  // ---- phase 4: MLP head (y lives in sG; wave w owns hidden cols [16w, 16w+16))
  f32x4 ha[2];
  ha[0] = fzero4();
  ha[1] = fzero4();
#pragma unroll 2
  for (int kt = 0; kt < 8; ++kt) {
    bf16x8 b = ldB(wsw + W1_OFF, kt * 8 + w, lane);
    const int kb = kt * 64 + kg4 * 16;
#pragma unroll
    for (int m = 0; m < 2; ++m) {
      bf16x8 a = ldA<512>(sG, m * 16 + l15, kb);
      ha[m] = mfma16(a, b, ha[m]);
    }
  }
  {
    const int colh = w * 16 + l15;
    const float bv1 = b1[colh], w2v = W2[colh];
    float o[8];
#pragma unroll
    for (int m = 0; m < 2; ++m)
#pragma unroll
      for (int r = 0; r < 4; ++r) {
        float hv = ha[m][r] + bv1;
        hv = 0.5f * hv * (1.0f + erff(hv * 0.70710678118654752f));
        o[m * 4 + r] = hv * w2v;
      }
    red16<8>(o);
    if (l15 < 2) {
#pragma unroll
      for (int r = 0; r < 4; ++r)
        sPO[w * 32 + l15 * 16 + kg4 * 4 + r] = o[l15 * 4 + r];
    }
  }
  __syncthreads();
  if (tid < 32) {
    float acc = b2[0];
#pragma unroll
    for (int ww = 0; ww < 8; ++ww) acc += sPO[ww * 32 + tid];
    out[(size_t)blk * 32 + tid] = acc;
  }
}

extern "C" void kernel_launch(void* const* d_in, const int* in_sizes, int n_in,
                              void* d_out, int out_size, void* d_ws, size_t ws_size,
                              hipStream_t stream) {
  (void)in_sizes; (void)n_in; (void)out_size; (void)ws_size;
  const float* gdiff = (const float*)d_in[0];
  const float* ldiff = (const float*)d_in[1];
  const float* Wg    = (const float*)d_in[2];
  const float* bg    = (const float*)d_in[3];
  const float* Wl    = (const float*)d_in[4];
  const float* bl    = (const float*)d_in[5];
  const float* Win   = (const float*)d_in[6];
  const float* bin   = (const float*)d_in[7];
  const float* Wout  = (const float*)d_in[8];
  const float* bout  = (const float*)d_in[9];
  const float* gamma = (const float*)d_in[10];
  const float* beta  = (const float*)d_in[11];
  const float* W1    = (const float*)d_in[12];
  const float* b1    = (const float*)d_in[13];
  const float* W2    = (const float*)d_in[14];
  const float* b2    = (const float*)d_in[15];
  unsigned short* ws = (unsigned short*)d_ws;
  float* out = (float*)d_out;

  convert_w<<<dim3((W_TOTAL + 255) / 256), dim3(256), 0, stream>>>(Wg, Wl, Win, Wout, W1, ws);
  dca_fused<<<dim3(2048), dim3(512), 0, stream>>>(gdiff, ldiff, bg, bl, bin, bout, gamma,
                                                  beta, b1, W2, b2,
                                                  (const unsigned short*)ws, out);
}